// Round 8
// baseline (258.594 us; speedup 1.0000x reference)
//
#include <hip/hip_runtime.h>
#include <stdint.h>

#define D_IN  256
#define D_OUT 128
#define NSEQ  4096
#define NB    16
#define TILE_M 64
#define GRID_M ((NB * NSEQ) / TILE_M)   // 1024 blocks
#define LDS_BYTES 32768                 // bufA + bufB, 16 KB each

typedef __bf16 bf16x8 __attribute__((ext_vector_type(8)));
typedef float  f32x4  __attribute__((ext_vector_type(4)));

__device__ __forceinline__ unsigned short f2bf(float f) {
  __bf16 h = (__bf16)f;
  union { __bf16 h; unsigned short u; } c; c.h = h;
  return c.u;
}
__device__ __forceinline__ float bf2f(unsigned short u) {
  union { unsigned int u; float f; } a; a.u = ((unsigned int)u) << 16;
  return a.f;
}

// prep: Wa = Wp @ W1 (exact fold: relu((X@Wp+bp)@W1+b1) = relu(X@Wa+be1)),
// W2 transpose, be1 = bp@W1 + b1, and zero the last-block counters.
__global__ __launch_bounds__(256) void prep(
    const float* __restrict__ Wp, const float* __restrict__ W1, const float* __restrict__ W2,
    const float* __restrict__ bp, const float* __restrict__ b1,
    unsigned short* __restrict__ WaT, unsigned short* __restrict__ W2T,
    float* __restrict__ be1, int* __restrict__ cnt) {
  int b = blockIdx.x;
  if (b < 128) {
    __shared__ float wp[256];
    int k0 = b * 2;
    wp[threadIdx.x] = Wp[k0 * 128 + threadIdx.x];
    __syncthreads();
    int kk = threadIdx.x >> 7, n = threadIdx.x & 127;
    float s = 0.f;
#pragma unroll 16
    for (int j = 0; j < 128; ++j) s += wp[kk * 128 + j] * W1[j * 128 + n];
    WaT[n * 256 + (k0 + kk)] = f2bf(s);
  } else if (b < 192) {
    int t = (b - 128) * 256 + threadIdx.x;
    int k = t >> 7, n = t & 127;
    W2T[n * 128 + k] = f2bf(W2[t]);
  } else {
    if (threadIdx.x < 128) {
      int n = threadIdx.x;
      float s = b1[n];
#pragma unroll 16
      for (int j = 0; j < 128; ++j) s += bp[j] * W1[j * 128 + n];
      be1[n] = s;
    }
    if (threadIdx.x < NB) cnt[threadIdx.x] = 0;   // ws is 0xAA-poisoned
  }
}

// 2 chained GEMMs per 64-row tile; BOTH X chunks loaded up front (single
// vmcnt drain), staged to bufA/bufB behind one barrier. B frags prefetched
// during barrier waits. Per-block col sums -> P; last block per batch
// reduces P -> S inline (threadfence + counter).
// LDS swizzle: (row,col) -> row*128 + ((col>>3 ^ (row&15))<<3) + (col&7).
template <bool USE_WS>
__global__ __launch_bounds__(256, 3) void fused2(
    const float* __restrict__ X,
    const unsigned short* __restrict__ WaT,
    const unsigned short* __restrict__ W2T,
    const float* __restrict__ be1, const float* __restrict__ b2v,
    unsigned short* __restrict__ Y3, float* __restrict__ out,
    float* __restrict__ P, float* __restrict__ S, int* __restrict__ cnt) {
  extern __shared__ unsigned short smem[];
  unsigned short* bufA = smem;            // 64x128 bf16 swizzled (k 0..127)
  unsigned short* bufB = smem + 8192;     // (k 128..255)
  __shared__ float red[128];
  __shared__ int isLast;

  const int tid  = threadIdx.x;
  const int lane = tid & 63;
  const int w    = tid >> 6;
  const int q    = lane >> 4;
  const int l16  = lane & 15;
  const int rowbase = blockIdx.x * TILE_M;
  const int bidx = blockIdx.x >> 6;       // 64 blocks per batch
  const int col0 = w * 32 + l16;
  const int col1 = col0 + 16;

  // ---- load BOTH X chunks (16 float4/thread, one outstanding-load window) ----
  float4 xv[16];
#pragma unroll
  for (int it = 0; it < 16; ++it) {
    int i = tid + it * 256;               // 4096 float4 = 64 rows x 64
    int r = i >> 6, c4 = (i & 63) << 2;
    xv[it] = *(const float4*)(X + (size_t)(rowbase + r) * D_IN + c4);
  }
  // ---- convert + stage into bufA/bufB ----
#pragma unroll
  for (int it = 0; it < 16; ++it) {
    int i = tid + it * 256;
    int r = i >> 6, c4 = (i & 63) << 2;
    unsigned short* dst = (c4 < 128) ? bufA : bufB;
    int cc = c4 & 127;
    ushort4 u; u.x = f2bf(xv[it].x); u.y = f2bf(xv[it].y); u.z = f2bf(xv[it].z); u.w = f2bf(xv[it].w);
    *(ushort4*)(dst + r * 128 + ((((cc >> 3) ^ (r & 15)) << 3) + (cc & 7))) = u;
  }

  // ---- issue Wa B-frag loads (fly during barrier #1) ----
  bf16x8 bA[4][2], bB[4][2];              // [ks][ct]
#pragma unroll
  for (int ks = 0; ks < 4; ++ks) {
    bA[ks][0] = *(const bf16x8*)(WaT + (size_t)col0 * 256 + ks * 32 + q * 8);
    bA[ks][1] = *(const bf16x8*)(WaT + (size_t)col1 * 256 + ks * 32 + q * 8);
    bB[ks][0] = *(const bf16x8*)(WaT + (size_t)col0 * 256 + 128 + ks * 32 + q * 8);
    bB[ks][1] = *(const bf16x8*)(WaT + (size_t)col1 * 256 + 128 + ks * 32 + q * 8);
  }
  __builtin_amdgcn_sched_barrier(0);      // don't sink the weight loads

  f32x4 acc[4][2];
#pragma unroll
  for (int rt = 0; rt < 4; ++rt) {
    acc[rt][0] = (f32x4){0.f, 0.f, 0.f, 0.f};
    acc[rt][1] = (f32x4){0.f, 0.f, 0.f, 0.f};
  }
  __syncthreads();   // #1: bufA+bufB staged

  // ---- GEMM-A: K=256 over both buffers ----
#pragma unroll
  for (int ks = 0; ks < 4; ++ks)
#pragma unroll
    for (int rt = 0; rt < 4; ++rt) {
      bf16x8 a = *(const bf16x8*)(bufA + (rt * 16 + l16) * 128 + (((4 * ks + q) ^ l16) << 3));
      acc[rt][0] = __builtin_amdgcn_mfma_f32_16x16x32_bf16(a, bA[ks][0], acc[rt][0], 0, 0, 0);
      acc[rt][1] = __builtin_amdgcn_mfma_f32_16x16x32_bf16(a, bA[ks][1], acc[rt][1], 0, 0, 0);
    }
#pragma unroll
  for (int ks = 0; ks < 4; ++ks)
#pragma unroll
    for (int rt = 0; rt < 4; ++rt) {
      bf16x8 a = *(const bf16x8*)(bufB + (rt * 16 + l16) * 128 + (((4 * ks + q) ^ l16) << 3));
      acc[rt][0] = __builtin_amdgcn_mfma_f32_16x16x32_bf16(a, bB[ks][0], acc[rt][0], 0, 0, 0);
      acc[rt][1] = __builtin_amdgcn_mfma_f32_16x16x32_bf16(a, bB[ks][1], acc[rt][1], 0, 0, 0);
    }

  // ---- issue W2 frag loads (reuse bA; fly during barrier #2) ----
#pragma unroll
  for (int ks = 0; ks < 4; ++ks) {
    bA[ks][0] = *(const bf16x8*)(W2T + (size_t)col0 * 128 + ks * 32 + q * 8);
    bA[ks][1] = *(const bf16x8*)(W2T + (size_t)col1 * 128 + ks * 32 + q * 8);
  }
  __builtin_amdgcn_sched_barrier(0);
  __syncthreads();   // #2: all waves done reading bufA

  // ---- epilogue A: Y2 = relu(acc + be1) -> bufA ----
  {
    const float e0 = be1[col0], e1 = be1[col1];
#pragma unroll
    for (int rt = 0; rt < 4; ++rt)
#pragma unroll
      for (int r = 0; r < 4; ++r) {
        int row = rt * 16 + q * 4 + r;
        int sw = (row & 15) << 3;
        float v0 = acc[rt][0][r] + e0; v0 = v0 > 0.f ? v0 : 0.f;
        float v1 = acc[rt][1][r] + e1; v1 = v1 > 0.f ? v1 : 0.f;
        bufA[row * 128 + ((((col0 >> 3) << 3) ^ sw) + (col0 & 7))] = f2bf(v0);
        bufA[row * 128 + ((((col1 >> 3) << 3) ^ sw) + (col1 & 7))] = f2bf(v1);
      }
  }
  __syncthreads();   // #3: Y2 visible

  // ---- GEMM-B (bufA, W2 frags) ----
#pragma unroll
  for (int rt = 0; rt < 4; ++rt) {
    acc[rt][0] = (f32x4){0.f, 0.f, 0.f, 0.f};
    acc[rt][1] = (f32x4){0.f, 0.f, 0.f, 0.f};
  }
#pragma unroll
  for (int ks = 0; ks < 4; ++ks)
#pragma unroll
    for (int rt = 0; rt < 4; ++rt) {
      bf16x8 a = *(const bf16x8*)(bufA + (rt * 16 + l16) * 128 + (((4 * ks + q) ^ l16) << 3));
      acc[rt][0] = __builtin_amdgcn_mfma_f32_16x16x32_bf16(a, bA[ks][0], acc[rt][0], 0, 0, 0);
      acc[rt][1] = __builtin_amdgcn_mfma_f32_16x16x32_bf16(a, bA[ks][1], acc[rt][1], 0, 0, 0);
    }

  // ---- epilogue B: Y3 = acc + b2 -> bufB; wave col sums -> P[block] ----
  {
    const float bb0 = b2v[col0], bb1 = b2v[col1];
    float s0 = 0.f, s1 = 0.f;
#pragma unroll
    for (int rt = 0; rt < 4; ++rt)
#pragma unroll
      for (int r = 0; r < 4; ++r) {
        int row = rt * 16 + q * 4 + r;
        int sw = (row & 15) << 3;
        float v0 = acc[rt][0][r] + bb0;
        float v1 = acc[rt][1][r] + bb1;
        s0 += v0; s1 += v1;
        bufB[row * 128 + ((((col0 >> 3) << 3) ^ sw) + (col0 & 7))] = f2bf(v0);
        bufB[row * 128 + ((((col1 >> 3) << 3) ^ sw) + (col1 & 7))] = f2bf(v1);
      }
    s0 += __shfl_down(s0, 16); s0 += __shfl_down(s0, 32);
    s1 += __shfl_down(s1, 16); s1 += __shfl_down(s1, 32);
    if (lane < 16) {
      P[(size_t)blockIdx.x * 128 + col0] = s0;
      P[(size_t)blockIdx.x * 128 + col1] = s1;
    }
  }
  __syncthreads();   // #4: Y3 in bufB complete

  // ---- copy-out ----
  if (USE_WS) {
#pragma unroll
    for (int it = 0; it < 4; ++it) {
      int i = tid + it * 256;
      int r = i >> 4, g = i & 15;
      *(uint4*)(Y3 + (size_t)(rowbase + r) * 128 + g * 8) =
          *(const uint4*)(bufB + r * 128 + ((g ^ (r & 15)) << 3));
    }
  } else {
#pragma unroll
    for (int it = 0; it < 8; ++it) {
      int i = tid + it * 256;
      int r = i >> 5, c4 = (i & 31) << 2;
      ushort4 u = *(const ushort4*)(bufB + r * 128 + ((((c4 >> 3) ^ (r & 15)) << 3) + (c4 & 7)));
      float4 v; v.x = bf2f(u.x); v.y = bf2f(u.y); v.z = bf2f(u.z); v.w = bf2f(u.w);
      *(float4*)(out + (size_t)(rowbase + r) * D_OUT + c4) = v;
    }
  }

  // ---- inline reduce: last block of each batch folds P -> S ----
  __threadfence();          // make this thread's P stores device-visible
  __syncthreads();
  if (tid == 0) {
    int old = atomicAdd(cnt + bidx, 1);
    isLast = (old == 63);
  }
  __syncthreads();
  if (isLast) {
    __threadfence();        // acquire: see all 64 blocks' P stores
    int col = tid & 127, h = tid >> 7;
    float s = 0.f;
#pragma unroll
    for (int i = 0; i < 32; ++i)
      s += P[(size_t)(bidx * 64 + h * 32 + i) * 128 + col];
    if (h == 1) red[col] = s;
    __syncthreads();
    if (h == 0) S[bidx * 128 + col] = s + red[col];
  }
}

// out[row][d] = S[b][d] - Y3_bf16[row][d]; 8 elems/thread
__global__ __launch_bounds__(256) void finalize_ws(
    float* __restrict__ out, const unsigned short* __restrict__ Y3, const float* __restrict__ S) {
  size_t g = (size_t)blockIdx.x * 256 + threadIdx.x;
  size_t base = g * 8;
  int row = (int)(base >> 7);
  int col = (int)(base & 127);
  int b = row >> 12;
  uint4 u = *(const uint4*)(Y3 + base);
  float4 s0 = *(const float4*)(S + (b << 7) + col);
  float4 s1 = *(const float4*)(S + (b << 7) + col + 4);
  union { unsigned int uu; float f; } t;
  float4 o0, o1;
  t.uu = u.x << 16;          o0.x = s0.x - t.f;
  t.uu = u.x & 0xFFFF0000u;  o0.y = s0.y - t.f;
  t.uu = u.y << 16;          o0.z = s0.z - t.f;
  t.uu = u.y & 0xFFFF0000u;  o0.w = s0.w - t.f;
  t.uu = u.z << 16;          o1.x = s1.x - t.f;
  t.uu = u.z & 0xFFFF0000u;  o1.y = s1.y - t.f;
  t.uu = u.w << 16;          o1.z = s1.z - t.f;
  t.uu = u.w & 0xFFFF0000u;  o1.w = s1.w - t.f;
  *(float4*)(out + base) = o0;
  *(float4*)(out + base + 4) = o1;
}

// fallback: out[row][d] = S[b][d] - out[row][d], in place
__global__ __launch_bounds__(256) void finalize_ip(float* __restrict__ out, const float* __restrict__ S) {
  size_t g = (size_t)blockIdx.x * 256 + threadIdx.x;
  size_t base = g * 8;
  int row = (int)(base >> 7);
  int col = (int)(base & 127);
  int b = row >> 12;
  float4 s0 = *(const float4*)(S + (b << 7) + col);
  float4 s1 = *(const float4*)(S + (b << 7) + col + 4);
  float4 y0 = *(const float4*)(out + base);
  float4 y1 = *(const float4*)(out + base + 4);
  float4 o0, o1;
  o0.x = s0.x - y0.x; o0.y = s0.y - y0.y; o0.z = s0.z - y0.z; o0.w = s0.w - y0.w;
  o1.x = s1.x - y1.x; o1.y = s1.y - y1.y; o1.z = s1.z - y1.z; o1.w = s1.w - y1.w;
  *(float4*)(out + base) = o0;
  *(float4*)(out + base + 4) = o1;
}

extern "C" void kernel_launch(void* const* d_in, const int* in_sizes, int n_in,
                              void* d_out, int out_size, void* d_ws, size_t ws_size,
                              hipStream_t stream) {
  const float* X  = (const float*)d_in[0];
  const float* Wp = (const float*)d_in[1];
  const float* bp = (const float*)d_in[2];
  const float* W1 = (const float*)d_in[3];
  const float* b1 = (const float*)d_in[4];
  const float* W2 = (const float*)d_in[5];
  const float* b2 = (const float*)d_in[6];
  float* out = (float*)d_out;

  char* ws = (char*)d_ws;
  float* S            = (float*)ws;                               // 8 KB
  float* be1          = (float*)(ws + 8192);                      // 2 KB
  int*   cnt          = (int*)(ws + 8192 + 2048);                 // 2 KB
  unsigned short* WaT = (unsigned short*)(ws + 12288);            // 64 KB (256x128 bf16 [n][k])
  unsigned short* W2T = (unsigned short*)(ws + 12288 + 65536);    // 32 KB
  float* P            = (float*)(ws + 12288 + 65536 + 32768);     // 512 KB (1024 x 128)
  unsigned short* Y3  = (unsigned short*)(ws + 12288 + 65536 + 32768 + 524288);  // 16 MB

  const size_t need = 12288 + 65536 + 32768 + 524288 + (size_t)NB * NSEQ * D_OUT * 2;
  const bool use_ws = ws_size >= need;

  prep<<<193, 256, 0, stream>>>(Wp, W1, W2, bp, b1, WaT, W2T, be1, cnt);

  const int fin_blocks = (NB * NSEQ * D_OUT) / (8 * 256);  // 4096
  if (use_ws) {
    fused2<true><<<GRID_M, 256, LDS_BYTES, stream>>>(X, WaT, W2T, be1, b2, Y3, out, P, S, cnt);
    finalize_ws<<<fin_blocks, 256, 0, stream>>>(out, Y3, S);
  } else {
    fused2<false><<<GRID_M, 256, LDS_BYTES, stream>>>(X, WaT, W2T, be1, b2, Y3, out, P, S, cnt);
    finalize_ip<<<fin_blocks, 256, 0, stream>>>(out, S);
  }
}